// Round 6
// baseline (230.060 us; speedup 1.0000x reference)
//
#include <hip/hip_runtime.h>
#include <hip/hip_bf16.h>
#include <math.h>

// Problem constants (B,T,C,H,D) = (8,1024,768,12,64)
#define B_ 8
#define T_ 1024
#define C_ 768
#define H_ 12
#define D_ 64
#define THREEC 2304

typedef short short8 __attribute__((ext_vector_type(8)));
typedef float f32x4 __attribute__((ext_vector_type(4)));

// ---------------------------------------------------------------------------
// MFMA via inline asm. D = A(16x32)*B(32x16) + C, bf16 in, f32 acc.
// A-frag: lane l holds A[l&15][(l>>4)*8+j]; B-frag: lane l holds B[(l>>4)*8+j][l&15]
// C/D: lane l reg j holds D[(l>>4)*4+j][l&15]   (m89-verified)
// ---------------------------------------------------------------------------
__device__ inline f32x4 mfma16(short8 a, short8 b, f32x4 c) {
    asm("v_mfma_f32_16x16x32_bf16 %0, %1, %2, %0" : "+v"(c) : "v"(a), "v"(b));
    return c;
}

// global -> LDS direct copy, 16B/lane, wave-uniform LDS base + lane*16 dest.
#define GLOAD16(gp, lp)                                                        \
    __builtin_amdgcn_global_load_lds(                                          \
        (const __attribute__((address_space(1))) unsigned int*)(gp),           \
        (__attribute__((address_space(3))) unsigned int*)(lp), 16, 0, 0)

__device__ inline unsigned short f2bf(float f) {
    __hip_bfloat16 h = __float2bfloat16(f);
    return *reinterpret_cast<unsigned short*>(&h);
}
__device__ inline unsigned int pack2bf(float lo, float hi) {
    return (unsigned int)f2bf(lo) | ((unsigned int)f2bf(hi) << 16);
}

// ---------------------------------------------------------------------------
// fp32 -> bf16 convert, 4 elems/thread.
// ---------------------------------------------------------------------------
__global__ __launch_bounds__(256) void cvt_f32_bf16_kernel(const float* __restrict__ src,
                                                           unsigned short* __restrict__ dst,
                                                           int n4) {
    int i = blockIdx.x * 256 + threadIdx.x;
    if (i >= n4) return;
    float4 v = ((const float4*)src)[i];
    ushort4 o;
    o.x = f2bf(v.x); o.y = f2bf(v.y); o.z = f2bf(v.z); o.w = f2bf(v.w);
    ((ushort4*)dst)[i] = o;
}

// ---------------------------------------------------------------------------
// RoPE tables [T][32]: ang(t,i) = t * 10000^(-i/32)
// ---------------------------------------------------------------------------
__global__ __launch_bounds__(256) void rope_table_kernel(float* __restrict__ cosT,
                                                         float* __restrict__ sinT) {
    int idx = blockIdx.x * 256 + threadIdx.x;
    int t = idx >> 5, i = idx & 31;
    float inv_freq = powf(10000.0f, -(float)i / 32.0f);
    float ang = (float)t * inv_freq;
    cosT[idx] = cosf(ang);
    sinT[idx] = sinf(ang);
}

// ---------------------------------------------------------------------------
// bf16 MFMA GEMM (NT), m97 structure: 128x128 tile, BK=32, 4 waves,
// 4x4 16x16 frags, global_load_lds w=16, linear LDS. Frag-read 8-way bank
// conflict left as-is: T2 swizzle is measured-null on 2-phase structures.
// ---------------------------------------------------------------------------
#define BM 128
#define BN 128
#define BKK 32

__global__ __launch_bounds__(256) void gemm_bt_mfma(const unsigned short* __restrict__ A,
                                                    const unsigned short* __restrict__ Bm,
                                                    float* __restrict__ Cm,
                                                    int M, int N, int K) {
    __shared__ short As[BM * BKK];
    __shared__ short Bs[BN * BKK];

    const int tid = threadIdx.x;
    const int w = tid >> 6, l = tid & 63;
    const int wr = w >> 1, wc = w & 1;
    const int row0 = blockIdx.x * BM, col0 = blockIdx.y * BN;

    const int srow = w * 16 + (l >> 2);
    const int scol = (l & 3) * 8;

    f32x4 acc[4][4];
#pragma unroll
    for (int m = 0; m < 4; ++m)
#pragma unroll
        for (int n = 0; n < 4; ++n) acc[m][n] = (f32x4){0.f, 0.f, 0.f, 0.f};

    const int fr = l & 15;
    const int fk = (l >> 4) * 8;

    for (int k0 = 0; k0 < K; k0 += BKK) {
        __syncthreads();
#pragma unroll
        for (int half = 0; half < 2; ++half) {
            int r = srow + half * 64;
            GLOAD16(&A[(size_t)(row0 + r) * K + k0 + scol], &As[(half * 64 + w * 16) * BKK]);
            GLOAD16(&Bm[(size_t)(col0 + r) * K + k0 + scol], &Bs[(half * 64 + w * 16) * BKK]);
        }
        __syncthreads();

        short8 af[4], bf[4];
#pragma unroll
        for (int m = 0; m < 4; ++m)
            af[m] = *(const short8*)&As[(wr * 64 + m * 16 + fr) * BKK + fk];
#pragma unroll
        for (int n = 0; n < 4; ++n)
            bf[n] = *(const short8*)&Bs[(wc * 64 + n * 16 + fr) * BKK + fk];
#pragma unroll
        for (int m = 0; m < 4; ++m)
#pragma unroll
            for (int n = 0; n < 4; ++n)
                acc[m][n] = mfma16(af[m], bf[n], acc[m][n]);
    }

    const int crow = (l >> 4) * 4;
    const int ccol = l & 15;
#pragma unroll
    for (int m = 0; m < 4; ++m)
#pragma unroll
        for (int n = 0; n < 4; ++n) {
            size_t base = (size_t)(row0 + wr * 64 + m * 16 + crow) * N + col0 + wc * 64 + n * 16 + ccol;
#pragma unroll
            for (int j = 0; j < 4; ++j) Cm[base + (size_t)j * N] = acc[m][n][j];
        }
}

// ---------------------------------------------------------------------------
// Prep: from fp32 qkv, produce  Kb [bh][1024][64] bf16 (RoPE applied)  and
// VT [bh][64][1024] bf16 (V transposed, via LDS tile).  One block per
// (b, h, 64-row t-tile), 256 threads.
// ---------------------------------------------------------------------------
__global__ __launch_bounds__(256) void prep_kernel(const float* __restrict__ qkv,
                                                   const float* __restrict__ cosT,
                                                   const float* __restrict__ sinT,
                                                   unsigned short* __restrict__ Kb,
                                                   unsigned short* __restrict__ VT) {
    const int tt = blockIdx.x, h = blockIdx.y, b = blockIdx.z;
    const int tid = threadIdx.x;
    const int bh = b * H_ + h;
    __shared__ unsigned short Vs[64][68];

    // --- K with RoPE: 2 passes x (32 rows x 8 threads, 4 d-pairs each) ---
#pragma unroll
    for (int p = 0; p < 2; ++p) {
        int tl = p * 32 + (tid >> 3);
        int t = tt * 64 + tl;
        int d0 = (tid & 7) * 4;
        const float* row = qkv + (size_t)(b * T_ + t) * THREEC + C_ + h * D_;
        float4 x0 = *(const float4*)(row + d0);
        float4 x1 = *(const float4*)(row + 32 + d0);
        float4 c = *(const float4*)(cosT + t * 32 + d0);
        float4 s = *(const float4*)(sinT + t * 32 + d0);
        ushort4 o0, o1;
        o0.x = f2bf(x0.x * c.x - x1.x * s.x);  o1.x = f2bf(x1.x * c.x + x0.x * s.x);
        o0.y = f2bf(x0.y * c.y - x1.y * s.y);  o1.y = f2bf(x1.y * c.y + x0.y * s.y);
        o0.z = f2bf(x0.z * c.z - x1.z * s.z);  o1.z = f2bf(x1.z * c.z + x0.z * s.z);
        o0.w = f2bf(x0.w * c.w - x1.w * s.w);  o1.w = f2bf(x1.w * c.w + x0.w * s.w);
        unsigned short* kout = Kb + ((size_t)bh * T_ + t) * D_;
        *(ushort4*)(kout + d0) = o0;
        *(ushort4*)(kout + 32 + d0) = o1;
    }

    // --- V -> LDS (bf16), then transposed write-out ---
    {
        int tl = tid >> 2;
        int t = tt * 64 + tl;
        int d0 = (tid & 3) * 16;
        const float* vrow = qkv + (size_t)(b * T_ + t) * THREEC + 2 * C_ + h * D_;
#pragma unroll
        for (int c4 = 0; c4 < 4; ++c4) {
            float4 v = *(const float4*)(vrow + d0 + c4 * 4);
            ushort4 u;
            u.x = f2bf(v.x); u.y = f2bf(v.y); u.z = f2bf(v.z); u.w = f2bf(v.w);
            *(ushort4*)&Vs[tl][d0 + c4 * 4] = u;
        }
    }
    __syncthreads();
    {
        int d = tid >> 2;
        int tc0 = (tid & 3) * 16;
        unsigned short tmp[16];
#pragma unroll
        for (int i = 0; i < 16; ++i) tmp[i] = Vs[tc0 + i][d];
        unsigned short* vout = VT + ((size_t)bh * D_ + d) * T_ + tt * 64 + tc0;
        union { short8 v; unsigned short u[8]; } a0, a1;
#pragma unroll
        for (int i = 0; i < 8; ++i) { a0.u[i] = tmp[i]; a1.u[i] = tmp[8 + i]; }
        *(short8*)vout = a0.v;
        *(short8*)(vout + 8) = a1.v;
    }
}

// ---------------------------------------------------------------------------
// MFMA causal flash attention. Block = (qblk of 64 rows, h, b), 4 waves x 16
// q-rows. Swapped QK^T (S^T = K x Q^T); P^T B-frag via 8 shfls; O^T = V^T x P^T.
//
// LDS XOR-swizzle (rule #21: both-sides-or-neither with global_load_lds):
//   Tiles are [64][64] bf16 = 128B row stride -> un-swizzled frag reads are a
//   16-way bank conflict (bank group = g*4, independent of c). We keep the LDS
//   dest linear, pre-swizzle the GLOBAL source column granule to
//   (l&7)^(l>>3), and read logical granule g at physical g^(row&7).
//   Involution: phys p of row r stores logical p^(r&7); reader wants g ->
//   reads p=g^(r&7) -> stored logical = g. Post-swizzle: 2-way (free).
// ---------------------------------------------------------------------------
__global__ __launch_bounds__(256) void attn_mfma_kernel(const float* __restrict__ qkv,
                                                        const unsigned short* __restrict__ Kb,
                                                        const unsigned short* __restrict__ VT,
                                                        const float* __restrict__ cosT,
                                                        const float* __restrict__ sinT,
                                                        unsigned short* __restrict__ ao_bf) {
    const int qblk = blockIdx.x, h = blockIdx.y, b = blockIdx.z;
    const int tid = threadIdx.x;
    const int w = tid >> 6, l = tid & 63;
    const int g = l >> 4, c = l & 15;
    const int bh = b * H_ + h;
    const float scale = 0.125f;

    __shared__ __align__(16) char smem[17408];
    unsigned short* Ks  = (unsigned short*)smem;            // [64][64] bf16, swizzled
    unsigned short* VTs = (unsigned short*)(smem + 8192);   // [64][64] bf16, swizzled
    float* Ot = (float*)smem;                               // epilogue [4][16][68]

    const int q_g = qblk * 64 + w * 16 + c;  // this lane's q column (global row)

    // ---- load + RoPE Q in-register: frag hh holds d = hh*32 + g*8 + j ----
    const float* qrow = qkv + ((size_t)(b * T_) + q_g) * THREEC + h * D_;
    float x0[8], x1[8], cv[8], sv[8];
    *(float4*)&x0[0] = *(const float4*)(qrow + g * 8);
    *(float4*)&x0[4] = *(const float4*)(qrow + g * 8 + 4);
    *(float4*)&x1[0] = *(const float4*)(qrow + 32 + g * 8);
    *(float4*)&x1[4] = *(const float4*)(qrow + 32 + g * 8 + 4);
    *(float4*)&cv[0] = *(const float4*)(cosT + q_g * 32 + g * 8);
    *(float4*)&cv[4] = *(const float4*)(cosT + q_g * 32 + g * 8 + 4);
    *(float4*)&sv[0] = *(const float4*)(sinT + q_g * 32 + g * 8);
    *(float4*)&sv[4] = *(const float4*)(sinT + q_g * 32 + g * 8 + 4);
    union { short8 v; unsigned short u[8]; } qa0, qa1;
#pragma unroll
    for (int j = 0; j < 8; ++j) {
        qa0.u[j] = f2bf(x0[j] * cv[j] - x1[j] * sv[j]);   // d in [0,32)
        qa1.u[j] = f2bf(x1[j] * cv[j] + x0[j] * sv[j]);   // d in [32,64)
    }

    f32x4 o[4];
#pragma unroll
    for (int db = 0; db < 4; ++db) o[db] = (f32x4){0.f, 0.f, 0.f, 0.f};
    float m = -INFINITY, lsum = 0.f;

    // staging source-granule swizzle (shorts); read-side physical granules
    const int sswz = ((l & 7) ^ (l >> 3)) * 8;
    const int sw0 = (g ^ (c & 7)) * 8;        // logical granule g   (cols g*8..)
    const int sw1 = ((g + 4) ^ (c & 7)) * 8;  // logical granule g+4 (cols 32+g*8..)

    const int ktiles = qblk + 1;
    for (int kt = 0; kt < ktiles; ++kt) {
        __syncthreads();  // previous tile's LDS reads done
#pragma unroll
        for (int sub = 0; sub < 2; ++sub) {
            int r = w * 16 + sub * 8 + (l >> 3);
            GLOAD16(Kb + ((size_t)bh * T_ + kt * 64 + r) * D_ + sswz,
                    Ks + (w * 16 + sub * 8) * 64);
            GLOAD16(VT + ((size_t)bh * D_ + r) * T_ + kt * 64 + sswz,
                    VTs + (w * 16 + sub * 8) * 64);
        }
        __syncthreads();  // staging complete (barrier drains vmcnt)

        // ---- S^T tiles: st[t] lane holds S^T[k = kt*64+t*16+g*4+j][q=c] ----
        f32x4 st[4];
#pragma unroll
        for (int t = 0; t < 4; ++t) {
            short8 k0 = *(const short8*)&Ks[(t * 16 + c) * 64 + sw0];
            short8 k1 = *(const short8*)&Ks[(t * 16 + c) * 64 + sw1];
            f32x4 z = (f32x4){0.f, 0.f, 0.f, 0.f};
            z = mfma16(k0, qa0.v, z);
            st[t] = mfma16(k1, qa1.v, z);
        }

        // ---- causal mask + scale; online softmax over this tile ----
        float p[16];
        float tmax = -INFINITY;
#pragma unroll
        for (int t = 0; t < 4; ++t)
#pragma unroll
            for (int j = 0; j < 4; ++j) {
                int kg = kt * 64 + t * 16 + g * 4 + j;
                float v = (kg <= q_g) ? st[t][j] * scale : -INFINITY;
                p[t * 4 + j] = v;
                tmax = fmaxf(tmax, v);
            }
        tmax = fmaxf(tmax, __shfl_xor(tmax, 16));
        tmax = fmaxf(tmax, __shfl_xor(tmax, 32));
        float mnew = fmaxf(m, tmax);           // finite after tile 0 (diag present)
        float corr = __expf(m - mnew);         // tile 0: exp(-inf)=0, o already 0
        m = mnew;
        float psum = 0.f;
#pragma unroll
        for (int i = 0; i < 16; ++i) { p[i] = __expf(p[i] - m); psum += p[i]; }
        psum += __shfl_xor(psum, 16);
        psum += __shfl_xor(psum, 32);
        lsum = lsum * corr + psum;
#pragma unroll
        for (int db = 0; db < 4; ++db)
#pragma unroll
            for (int j = 0; j < 4; ++j) o[db][j] *= corr;

        // ---- pack P rows to bf16 pairs: u[t][p2] = (k = t*16+g*4+2p2, +1) ----
        unsigned int u[4][2];
#pragma unroll
        for (int t = 0; t < 4; ++t) {
            u[t][0] = pack2bf(p[t * 4 + 0], p[t * 4 + 1]);
            u[t][1] = pack2bf(p[t * 4 + 2], p[t * 4 + 3]);
        }

        // ---- redistribute to P^T B-frags via 8 shfls (desk-verified):
        // target lane (g,c) word wd of kb needs u[kb*2+(g>>1)][wd&1] from lane
        // ((g&1)*2+(wd>>1))*16+c; varA/varB selects are evaluated on the
        // SOURCE lane, whose g' satisfies g'&1 == g>>1 (A) / (g>>1)^1 (B).
        const int srcA = (((g & 1) << 1) | (g >> 1)) * 16 + c;
        const int srcB = (((g & 1) << 1) | ((g >> 1) ^ 1)) * 16 + c;
        const int hi = g >> 1;
        union { short8 v; unsigned int w[4]; } pb[2];
#pragma unroll
        for (int kb = 0; kb < 2; ++kb)
#pragma unroll
            for (int p2 = 0; p2 < 2; ++p2) {
                unsigned int varA = (g & 1) ? u[kb * 2 + 1][p2] : u[kb * 2][p2];
                unsigned int varB = (g & 1) ? u[kb * 2][p2] : u[kb * 2 + 1][p2];
                unsigned int wA = __shfl(varA, srcA, 64);
                unsigned int wB = __shfl(varB, srcB, 64);
                pb[kb].w[p2]     = hi ? wB : wA;
                pb[kb].w[p2 + 2] = hi ? wA : wB;
            }

        // ---- O^T += V^T x P^T : o[db] lane holds O^T[d=db*16+g*4+j][q=c] ----
#pragma unroll
        for (int db = 0; db < 4; ++db) {
            short8 va0 = *(const short8*)&VTs[(db * 16 + c) * 64 + sw0];
            short8 va1 = *(const short8*)&VTs[(db * 16 + c) * 64 + sw1];
            o[db] = mfma16(va0, pb[0].v, o[db]);
            o[db] = mfma16(va1, pb[1].v, o[db]);
        }
    }

    // ---- epilogue: LDS transpose O^T -> [q][d], write bf16 coalesced ----
    __syncthreads();  // all waves done with Ks/VTs before overlay
    const float inv = 1.0f / lsum;
    float* ow = Ot + w * 1088;  // wave-private [16][68]
#pragma unroll
    for (int db = 0; db < 4; ++db)
#pragma unroll
        for (int j = 0; j < 4; ++j)
            ow[c * 68 + db * 16 + g * 4 + j] = o[db][j] * inv;
    __syncthreads();  // write->read ordering (block-wide, safe)
    {
        const float* orow = ow + c * 68 + g * 16;
        f32x4 v0 = *(const f32x4*)(orow);
        f32x4 v1 = *(const f32x4*)(orow + 4);
        f32x4 v2 = *(const f32x4*)(orow + 8);
        f32x4 v3 = *(const f32x4*)(orow + 12);
        union { short8 v; unsigned int w[4]; } s0, s1;
        s0.w[0] = pack2bf(v0[0], v0[1]); s0.w[1] = pack2bf(v0[2], v0[3]);
        s0.w[2] = pack2bf(v1[0], v1[1]); s0.w[3] = pack2bf(v1[2], v1[3]);
        s1.w[0] = pack2bf(v2[0], v2[1]); s1.w[1] = pack2bf(v2[2], v2[3]);
        s1.w[2] = pack2bf(v3[0], v3[1]); s1.w[3] = pack2bf(v3[2], v3[3]);
        unsigned short* op = ao_bf + ((size_t)(b * T_) + qblk * 64 + w * 16 + c) * C_ + h * D_ + g * 16;
        *(short8*)op = s0.v;
        *(short8*)(op + 8) = s1.v;
    }
}

// ---------------------------------------------------------------------------
// Launch: cvt x3 -> tables -> qkv GEMM -> prep (K rope + V^T) -> attn -> proj
// ---------------------------------------------------------------------------
extern "C" void kernel_launch(void* const* d_in, const int* in_sizes, int n_in,
                              void* d_out, int out_size, void* d_ws, size_t ws_size,
                              hipStream_t stream) {
    const float* x      = (const float*)d_in[0];   // [8192, 768]
    const float* w_qkv  = (const float*)d_in[1];   // [2304, 768]
    const float* w_proj = (const float*)d_in[2];   // [768, 768]
    float* out = (float*)d_out;                    // [8192, 768]

    float* ws   = (float*)d_ws;
    float* qkv  = ws;                              // 18,874,368 f32 (raw QKV)
    float* cosT = ws + 18874368;                   // 32,768 f32
    float* sinT = ws + 18907136;                   // 32,768 f32
    unsigned short* x_bf  = (unsigned short*)(ws + 18939904);  // 6,291,456 bf16
    unsigned short* wq_bf = x_bf + 6291456;        // 1,769,472
    unsigned short* wp_bf = wq_bf + 1769472;       // 589,824
    unsigned short* ao_bf = wp_bf + 589824;        // 6,291,456 (attn out, bf16)
    unsigned short* Kb    = ao_bf + 6291456;       // 6,291,456 (roped K)
    unsigned short* VT    = Kb + 6291456;          // 6,291,456 (V transposed)
    // total ~123 MB

    cvt_f32_bf16_kernel<<<6291456 / 4 / 256, 256, 0, stream>>>(x, x_bf, 6291456 / 4);
    cvt_f32_bf16_kernel<<<1769472 / 4 / 256, 256, 0, stream>>>(w_qkv, wq_bf, 1769472 / 4);
    cvt_f32_bf16_kernel<<<589824 / 4 / 256, 256, 0, stream>>>(w_proj, wp_bf, 589824 / 4);
    rope_table_kernel<<<(T_ * 32) / 256, 256, 0, stream>>>(cosT, sinT);

    // qkv = x @ w_qkv^T : M=8192, N=2304, K=768
    gemm_bt_mfma<<<dim3(8192 / BM, 2304 / BN), 256, 0, stream>>>(x_bf, wq_bf, qkv, 8192, 2304, 768);

    prep_kernel<<<dim3(T_ / 64, H_, B_), 256, 0, stream>>>(qkv, cosT, sinT, Kb, VT);

    attn_mfma_kernel<<<dim3(T_ / 64, H_, B_), 256, 0, stream>>>(qkv, Kb, VT, cosT, sinT, ao_bf);

    // out = attnout @ w_proj^T : M=8192, N=768, K=768
    gemm_bt_mfma<<<dim3(8192 / BM, 768 / BN), 256, 0, stream>>>(ao_bf, wp_bf, out, 8192, 768, 768);
}

// Round 8
// 219.921 us; speedup vs baseline: 1.0461x; 1.0461x over previous
//
#include <hip/hip_runtime.h>
#include <hip/hip_bf16.h>
#include <math.h>

// Problem constants (B,T,C,H,D) = (8,1024,768,12,64)
#define B_ 8
#define T_ 1024
#define C_ 768
#define H_ 12
#define D_ 64
#define THREEC 2304

typedef short short8 __attribute__((ext_vector_type(8)));
typedef float f32x4 __attribute__((ext_vector_type(4)));

// ---------------------------------------------------------------------------
// MFMA via inline asm. D = A(16x32)*B(32x16) + C, bf16 in, f32 acc.
// A-frag: lane l holds A[l&15][(l>>4)*8+j]; B-frag: lane l holds B[(l>>4)*8+j][l&15]
// C/D: lane l reg j holds D[(l>>4)*4+j][l&15]   (m89-verified)
// ---------------------------------------------------------------------------
__device__ inline f32x4 mfma16(short8 a, short8 b, f32x4 c) {
    asm("v_mfma_f32_16x16x32_bf16 %0, %1, %2, %0" : "+v"(c) : "v"(a), "v"(b));
    return c;
}

// global -> LDS direct copy, 16B/lane, wave-uniform LDS base + lane*16 dest.
#define GLOAD16(gp, lp)                                                        \
    __builtin_amdgcn_global_load_lds(                                          \
        (const __attribute__((address_space(1))) unsigned int*)(gp),           \
        (__attribute__((address_space(3))) unsigned int*)(lp), 16, 0, 0)

__device__ inline unsigned short f2bf(float f) {
    __hip_bfloat16 h = __float2bfloat16(f);
    return *reinterpret_cast<unsigned short*>(&h);
}
__device__ inline unsigned int pack2bf(float lo, float hi) {
    return (unsigned int)f2bf(lo) | ((unsigned int)f2bf(hi) << 16);
}

// ---------------------------------------------------------------------------
// fp32 -> bf16 convert, 4 elems/thread.
// ---------------------------------------------------------------------------
__global__ __launch_bounds__(256) void cvt_f32_bf16_kernel(const float* __restrict__ src,
                                                           unsigned short* __restrict__ dst,
                                                           int n4) {
    int i = blockIdx.x * 256 + threadIdx.x;
    if (i >= n4) return;
    float4 v = ((const float4*)src)[i];
    ushort4 o;
    o.x = f2bf(v.x); o.y = f2bf(v.y); o.z = f2bf(v.z); o.w = f2bf(v.w);
    ((ushort4*)dst)[i] = o;
}

// ---------------------------------------------------------------------------
// RoPE tables [T][32]: ang(t,i) = t * 10000^(-i/32)
// ---------------------------------------------------------------------------
__global__ __launch_bounds__(256) void rope_table_kernel(float* __restrict__ cosT,
                                                         float* __restrict__ sinT) {
    int idx = blockIdx.x * 256 + threadIdx.x;
    int t = idx >> 5, i = idx & 31;
    float inv_freq = powf(10000.0f, -(float)i / 32.0f);
    float ang = (float)t * inv_freq;
    cosT[idx] = cosf(ang);
    sinT[idx] = sinf(ang);
}

// ---------------------------------------------------------------------------
// bf16 MFMA GEMM (NT), m97 structure (unchanged, HW-verified R6 bench):
// 128x128 tile, BK=32, 4 waves, 4x4 16x16 frags, global_load_lds w=16.
// ---------------------------------------------------------------------------
#define BM 128
#define BN 128
#define BKK 32

__global__ __launch_bounds__(256) void gemm_bt_mfma(const unsigned short* __restrict__ A,
                                                    const unsigned short* __restrict__ Bm,
                                                    float* __restrict__ Cm,
                                                    int M, int N, int K) {
    __shared__ short As[BM * BKK];
    __shared__ short Bs[BN * BKK];

    const int tid = threadIdx.x;
    const int w = tid >> 6, l = tid & 63;
    const int wr = w >> 1, wc = w & 1;
    const int row0 = blockIdx.x * BM, col0 = blockIdx.y * BN;

    const int srow = w * 16 + (l >> 2);
    const int scol = (l & 3) * 8;

    f32x4 acc[4][4];
#pragma unroll
    for (int m = 0; m < 4; ++m)
#pragma unroll
        for (int n = 0; n < 4; ++n) acc[m][n] = (f32x4){0.f, 0.f, 0.f, 0.f};

    const int fr = l & 15;
    const int fk = (l >> 4) * 8;

    for (int k0 = 0; k0 < K; k0 += BKK) {
        __syncthreads();
#pragma unroll
        for (int half = 0; half < 2; ++half) {
            int r = srow + half * 64;
            GLOAD16(&A[(size_t)(row0 + r) * K + k0 + scol], &As[(half * 64 + w * 16) * BKK]);
            GLOAD16(&Bm[(size_t)(col0 + r) * K + k0 + scol], &Bs[(half * 64 + w * 16) * BKK]);
        }
        __syncthreads();

        short8 af[4], bf[4];
#pragma unroll
        for (int m = 0; m < 4; ++m)
            af[m] = *(const short8*)&As[(wr * 64 + m * 16 + fr) * BKK + fk];
#pragma unroll
        for (int n = 0; n < 4; ++n)
            bf[n] = *(const short8*)&Bs[(wc * 64 + n * 16 + fr) * BKK + fk];
#pragma unroll
        for (int m = 0; m < 4; ++m)
#pragma unroll
            for (int n = 0; n < 4; ++n)
                acc[m][n] = mfma16(af[m], bf[n], acc[m][n]);
    }

    const int crow = (l >> 4) * 4;
    const int ccol = l & 15;
#pragma unroll
    for (int m = 0; m < 4; ++m)
#pragma unroll
        for (int n = 0; n < 4; ++n) {
            size_t base = (size_t)(row0 + wr * 64 + m * 16 + crow) * N + col0 + wc * 64 + n * 16 + ccol;
#pragma unroll
            for (int j = 0; j < 4; ++j) Cm[base + (size_t)j * N] = acc[m][n][j];
        }
}

// ---------------------------------------------------------------------------
// Prep: from fp32 qkv, produce  Kb [bh][1024][64] bf16 (RoPE applied)  and
// VT [bh][64][1024] bf16 (V transposed, via LDS tile). (HW-verified R6 bench)
// ---------------------------------------------------------------------------
__global__ __launch_bounds__(256) void prep_kernel(const float* __restrict__ qkv,
                                                   const float* __restrict__ cosT,
                                                   const float* __restrict__ sinT,
                                                   unsigned short* __restrict__ Kb,
                                                   unsigned short* __restrict__ VT) {
    const int tt = blockIdx.x, h = blockIdx.y, b = blockIdx.z;
    const int tid = threadIdx.x;
    const int bh = b * H_ + h;
    __shared__ unsigned short Vs[64][68];

#pragma unroll
    for (int p = 0; p < 2; ++p) {
        int tl = p * 32 + (tid >> 3);
        int t = tt * 64 + tl;
        int d0 = (tid & 7) * 4;
        const float* row = qkv + (size_t)(b * T_ + t) * THREEC + C_ + h * D_;
        float4 x0 = *(const float4*)(row + d0);
        float4 x1 = *(const float4*)(row + 32 + d0);
        float4 c = *(const float4*)(cosT + t * 32 + d0);
        float4 s = *(const float4*)(sinT + t * 32 + d0);
        ushort4 o0, o1;
        o0.x = f2bf(x0.x * c.x - x1.x * s.x);  o1.x = f2bf(x1.x * c.x + x0.x * s.x);
        o0.y = f2bf(x0.y * c.y - x1.y * s.y);  o1.y = f2bf(x1.y * c.y + x0.y * s.y);
        o0.z = f2bf(x0.z * c.z - x1.z * s.z);  o1.z = f2bf(x1.z * c.z + x0.z * s.z);
        o0.w = f2bf(x0.w * c.w - x1.w * s.w);  o1.w = f2bf(x1.w * c.w + x0.w * s.w);
        unsigned short* kout = Kb + ((size_t)bh * T_ + t) * D_;
        *(ushort4*)(kout + d0) = o0;
        *(ushort4*)(kout + 32 + d0) = o1;
    }

    {
        int tl = tid >> 2;
        int t = tt * 64 + tl;
        int d0 = (tid & 3) * 16;
        const float* vrow = qkv + (size_t)(b * T_ + t) * THREEC + 2 * C_ + h * D_;
#pragma unroll
        for (int c4 = 0; c4 < 4; ++c4) {
            float4 v = *(const float4*)(vrow + d0 + c4 * 4);
            ushort4 u;
            u.x = f2bf(v.x); u.y = f2bf(v.y); u.z = f2bf(v.z); u.w = f2bf(v.w);
            *(ushort4*)&Vs[tl][d0 + c4 * 4] = u;
        }
    }
    __syncthreads();
    {
        int d = tid >> 2;
        int tc0 = (tid & 3) * 16;
        unsigned short tmp[16];
#pragma unroll
        for (int i = 0; i < 16; ++i) tmp[i] = Vs[tc0 + i][d];
        unsigned short* vout = VT + ((size_t)bh * D_ + d) * T_ + tt * 64 + tc0;
        union { short8 v; unsigned short u[8]; } a0, a1;
#pragma unroll
        for (int i = 0; i < 8; ++i) { a0.u[i] = tmp[i]; a1.u[i] = tmp[8 + i]; }
        *(short8*)vout = a0.v;
        *(short8*)(vout + 8) = a1.v;
    }
}

// ---------------------------------------------------------------------------
// MFMA causal flash attention, v2-bisect: QBLK=128 (8 waves), R5-proven
// 2-barrier single-buffer staging (double-buffer REVERTED pending asm
// evidence of barrier vmcnt lowering), reversed qblk order, wave-uniform
// skip/fast-path, scale folded into Q. Swizzle as R5 (HW-verified).
// ---------------------------------------------------------------------------
#define QBLK 128

__global__ __launch_bounds__(512) void attn_mfma_kernel(const float* __restrict__ qkv,
                                                        const unsigned short* __restrict__ Kb,
                                                        const unsigned short* __restrict__ VT,
                                                        const float* __restrict__ cosT,
                                                        const float* __restrict__ sinT,
                                                        unsigned short* __restrict__ ao_bf) {
    const int qblk = (T_ / QBLK - 1) - blockIdx.x;  // heavy blocks first
    const int h = blockIdx.y, b = blockIdx.z;
    const int tid = threadIdx.x;
    const int w = tid >> 6, l = tid & 63;           // w = 0..7
    const int g = l >> 4, c = l & 15;
    const int bh = b * H_ + h;

    // staging: K @0 (8KB), V @8192 (8KB); epilogue Ot overlays all 34816B
    __shared__ __align__(16) char smem[34816];
    float* Ot = (float*)smem;  // [8 waves][16][68] f32

    const int q_g = qblk * QBLK + w * 16 + c;  // this lane's q row

    // ---- load + RoPE Q in-register, pre-scaled by 2^-3 (exact in bf16) ----
    const float* qrow = qkv + ((size_t)(b * T_) + q_g) * THREEC + h * D_;
    float x0[8], x1[8], cv[8], sv[8];
    *(float4*)&x0[0] = *(const float4*)(qrow + g * 8);
    *(float4*)&x0[4] = *(const float4*)(qrow + g * 8 + 4);
    *(float4*)&x1[0] = *(const float4*)(qrow + 32 + g * 8);
    *(float4*)&x1[4] = *(const float4*)(qrow + 32 + g * 8 + 4);
    *(float4*)&cv[0] = *(const float4*)(cosT + q_g * 32 + g * 8);
    *(float4*)&cv[4] = *(const float4*)(cosT + q_g * 32 + g * 8 + 4);
    *(float4*)&sv[0] = *(const float4*)(sinT + q_g * 32 + g * 8);
    *(float4*)&sv[4] = *(const float4*)(sinT + q_g * 32 + g * 8 + 4);
    union { short8 v; unsigned short u[8]; } qa0, qa1;
#pragma unroll
    for (int j = 0; j < 8; ++j) {
        qa0.u[j] = f2bf((x0[j] * cv[j] - x1[j] * sv[j]) * 0.125f);  // d in [0,32)
        qa1.u[j] = f2bf((x1[j] * cv[j] + x0[j] * sv[j]) * 0.125f);  // d in [32,64)
    }

    f32x4 o[4];
#pragma unroll
    for (int db = 0; db < 4; ++db) o[db] = (f32x4){0.f, 0.f, 0.f, 0.f};
    float m = -INFINITY, lsum = 0.f;

    // staging source-granule swizzle; read-side physical granules
    const int sswz = ((l & 7) ^ (l >> 3)) * 8;
    const int sw0 = (g ^ (c & 7)) * 8;        // logical granule g
    const int sw1 = ((g + 4) ^ (c & 7)) * 8;  // logical granule g+4
    const int srow = w * 8 + (l >> 3);        // staging row 0..63 (8 rows/wave)

    const unsigned short* Ks  = (const unsigned short*)smem;
    const unsigned short* VTs = (const unsigned short*)(smem + 8192);

    const int ktiles = 2 * qblk + 2;
    for (int kt = 0; kt < ktiles; ++kt) {
        __syncthreads();  // all waves done reading previous tile
        GLOAD16(Kb + ((size_t)bh * T_ + kt * 64 + srow) * D_ + sswz,
                (unsigned short*)smem + (w * 8) * 64);
        GLOAD16(VT + ((size_t)bh * D_ + srow) * T_ + kt * 64 + sswz,
                (unsigned short*)(smem + 8192) + (w * 8) * 64);
        __syncthreads();  // staging complete (R5-proven pattern)

        // wave-uniform skip: this wave's rows are all above the tile
        if (kt * 64 > qblk * QBLK + w * 16 + 15) continue;

        // ---- S^T tiles: st[t] lane holds S^T[k = kt*64+t*16+g*4+j][q=c] ----
        f32x4 st[4];
#pragma unroll
        for (int t = 0; t < 4; ++t) {
            short8 k0 = *(const short8*)&Ks[(t * 16 + c) * 64 + sw0];
            short8 k1 = *(const short8*)&Ks[(t * 16 + c) * 64 + sw1];
            f32x4 z = (f32x4){0.f, 0.f, 0.f, 0.f};
            z = mfma16(k0, qa0.v, z);
            st[t] = mfma16(k1, qa1.v, z);
        }

        // ---- causal mask (wave-uniform fast path when tile fully unmasked) ----
        float p[16];
        float tmax = -INFINITY;
        if (kt * 64 + 63 <= qblk * QBLK + w * 16) {
#pragma unroll
            for (int t = 0; t < 4; ++t)
#pragma unroll
                for (int j = 0; j < 4; ++j) {
                    p[t * 4 + j] = st[t][j];
                    tmax = fmaxf(tmax, st[t][j]);
                }
        } else {
#pragma unroll
            for (int t = 0; t < 4; ++t)
#pragma unroll
                for (int j = 0; j < 4; ++j) {
                    int kg = kt * 64 + t * 16 + g * 4 + j;
                    float v = (kg <= q_g) ? st[t][j] : -INFINITY;
                    p[t * 4 + j] = v;
                    tmax = fmaxf(tmax, v);
                }
        }
        tmax = fmaxf(tmax, __shfl_xor(tmax, 16));
        tmax = fmaxf(tmax, __shfl_xor(tmax, 32));
        float mnew = fmaxf(m, tmax);           // finite after tile 0 (diag present)
        float corr = __expf(m - mnew);         // tile 0: exp(-inf)=0, o already 0
        m = mnew;
        float psum = 0.f;
#pragma unroll
        for (int i = 0; i < 16; ++i) { p[i] = __expf(p[i] - m); psum += p[i]; }
        psum += __shfl_xor(psum, 16);
        psum += __shfl_xor(psum, 32);
        lsum = lsum * corr + psum;
#pragma unroll
        for (int db = 0; db < 4; ++db)
#pragma unroll
            for (int j = 0; j < 4; ++j) o[db][j] *= corr;

        // ---- pack P rows to bf16 pairs ----
        unsigned int u[4][2];
#pragma unroll
        for (int t = 0; t < 4; ++t) {
            u[t][0] = pack2bf(p[t * 4 + 0], p[t * 4 + 1]);
            u[t][1] = pack2bf(p[t * 4 + 2], p[t * 4 + 3]);
        }

        // ---- redistribute to P^T B-frags via 8 shfls (HW-verified R5) ----
        const int srcA = (((g & 1) << 1) | (g >> 1)) * 16 + c;
        const int srcB = (((g & 1) << 1) | ((g >> 1) ^ 1)) * 16 + c;
        const int hi = g >> 1;
        union { short8 v; unsigned int w[4]; } pb[2];
#pragma unroll
        for (int kb = 0; kb < 2; ++kb)
#pragma unroll
            for (int p2 = 0; p2 < 2; ++p2) {
                unsigned int varA = (g & 1) ? u[kb * 2 + 1][p2] : u[kb * 2][p2];
                unsigned int varB = (g & 1) ? u[kb * 2][p2] : u[kb * 2 + 1][p2];
                unsigned int wA = __shfl(varA, srcA, 64);
                unsigned int wB = __shfl(varB, srcB, 64);
                pb[kb].w[p2]     = hi ? wB : wA;
                pb[kb].w[p2 + 2] = hi ? wA : wB;
            }

        // ---- O^T += V^T x P^T : o[db] lane holds O^T[d=db*16+g*4+j][q=c] ----
#pragma unroll
        for (int db = 0; db < 4; ++db) {
            short8 va0 = *(const short8*)&VTs[(db * 16 + c) * 64 + sw0];
            short8 va1 = *(const short8*)&VTs[(db * 16 + c) * 64 + sw1];
            o[db] = mfma16(va0, pb[0].v, o[db]);
            o[db] = mfma16(va1, pb[1].v, o[db]);
        }
    }

    // ---- epilogue: LDS transpose O^T -> [q][d], write bf16 coalesced ----
    __syncthreads();  // all waves done with staging buffers before overlay
    const float inv = 1.0f / lsum;
    float* ow = Ot + w * 1088;  // wave-private [16][68]
#pragma unroll
    for (int db = 0; db < 4; ++db)
#pragma unroll
        for (int j = 0; j < 4; ++j)
            ow[c * 68 + db * 16 + g * 4 + j] = o[db][j] * inv;
    __syncthreads();
    {
        const float* orow = ow + c * 68 + g * 16;
        f32x4 v0 = *(const f32x4*)(orow);
        f32x4 v1 = *(const f32x4*)(orow + 4);
        f32x4 v2 = *(const f32x4*)(orow + 8);
        f32x4 v3 = *(const f32x4*)(orow + 12);
        union { short8 v; unsigned int w[4]; } s0, s1;
        s0.w[0] = pack2bf(v0[0], v0[1]); s0.w[1] = pack2bf(v0[2], v0[3]);
        s0.w[2] = pack2bf(v1[0], v1[1]); s0.w[3] = pack2bf(v1[2], v1[3]);
        s1.w[0] = pack2bf(v2[0], v2[1]); s1.w[1] = pack2bf(v2[2], v2[3]);
        s1.w[2] = pack2bf(v3[0], v3[1]); s1.w[3] = pack2bf(v3[2], v3[3]);
        unsigned short* op = ao_bf + ((size_t)(b * T_) + qblk * QBLK + w * 16 + c) * C_ + h * D_ + g * 16;
        *(short8*)op = s0.v;
        *(short8*)(op + 8) = s1.v;
    }
}

// ---------------------------------------------------------------------------
// Launch: cvt x3 -> tables -> qkv GEMM -> prep (K rope + V^T) -> attn -> proj
// ---------------------------------------------------------------------------
extern "C" void kernel_launch(void* const* d_in, const int* in_sizes, int n_in,
                              void* d_out, int out_size, void* d_ws, size_t ws_size,
                              hipStream_t stream) {
    const float* x      = (const float*)d_in[0];   // [8192, 768]
    const float* w_qkv  = (const float*)d_in[1];   // [2304, 768]
    const float* w_proj = (const float*)d_in[2];   // [768, 768]
    float* out = (float*)d_out;                    // [8192, 768]

    float* ws   = (float*)d_ws;
    float* qkv  = ws;                              // 18,874,368 f32 (raw QKV)
    float* cosT = ws + 18874368;                   // 32,768 f32
    float* sinT = ws + 18907136;                   // 32,768 f32
    unsigned short* x_bf  = (unsigned short*)(ws + 18939904);  // 6,291,456 bf16
    unsigned short* wq_bf = x_bf + 6291456;        // 1,769,472
    unsigned short* wp_bf = wq_bf + 1769472;       // 589,824
    unsigned short* ao_bf = wp_bf + 589824;        // 6,291,456 (attn out, bf16)
    unsigned short* Kb    = ao_bf + 6291456;       // 6,291,456 (roped K)
    unsigned short* VT    = Kb + 6291456;          // 6,291,456 (V transposed)

    cvt_f32_bf16_kernel<<<6291456 / 4 / 256, 256, 0, stream>>>(x, x_bf, 6291456 / 4);
    cvt_f32_bf16_kernel<<<1769472 / 4 / 256, 256, 0, stream>>>(w_qkv, wq_bf, 1769472 / 4);
    cvt_f32_bf16_kernel<<<589824 / 4 / 256, 256, 0, stream>>>(w_proj, wp_bf, 589824 / 4);
    rope_table_kernel<<<(T_ * 32) / 256, 256, 0, stream>>>(cosT, sinT);

    // qkv = x @ w_qkv^T : M=8192, N=2304, K=768
    gemm_bt_mfma<<<dim3(8192 / BM, 2304 / BN), 256, 0, stream>>>(x_bf, wq_bf, qkv, 8192, 2304, 768);

    prep_kernel<<<dim3(T_ / 64, H_, B_), 256, 0, stream>>>(qkv, cosT, sinT, Kb, VT);

    attn_mfma_kernel<<<dim3(T_ / QBLK, H_, B_), 512, 0, stream>>>(qkv, Kb, VT, cosT, sinT, ao_bf);

    // out = attnout @ w_proj^T : M=8192, N=768, K=768
    gemm_bt_mfma<<<dim3(8192 / BM, 768 / BN), 256, 0, stream>>>(ao_bf, wp_bf, out, 8192, 768, 768);
}

// Round 9
// 219.680 us; speedup vs baseline: 1.0473x; 1.0011x over previous
//
#include <hip/hip_runtime.h>
#include <hip/hip_bf16.h>
#include <math.h>

// Problem constants (B,T,C,H,D) = (8,1024,768,12,64)
#define B_ 8
#define T_ 1024
#define C_ 768
#define H_ 12
#define D_ 64
#define THREEC 2304

typedef short short8 __attribute__((ext_vector_type(8)));
typedef float f32x4 __attribute__((ext_vector_type(4)));

// ---------------------------------------------------------------------------
// MFMA via inline asm. D = A(16x32)*B(32x16) + C, bf16 in, f32 acc.
// A-frag: lane l holds A[l&15][(l>>4)*8+j]; B-frag: lane l holds B[(l>>4)*8+j][l&15]
// C/D: lane l reg j holds D[(l>>4)*4+j][l&15]   (m89-verified)
// ---------------------------------------------------------------------------
__device__ inline f32x4 mfma16(short8 a, short8 b, f32x4 c) {
    asm("v_mfma_f32_16x16x32_bf16 %0, %1, %2, %0" : "+v"(c) : "v"(a), "v"(b));
    return c;
}

// global -> LDS direct copy, 16B/lane, wave-uniform LDS base + lane*16 dest.
#define GLOAD16(gp, lp)                                                        \
    __builtin_amdgcn_global_load_lds(                                          \
        (const __attribute__((address_space(1))) unsigned int*)(gp),           \
        (__attribute__((address_space(3))) unsigned int*)(lp), 16, 0, 0)

__device__ inline unsigned short f2bf(float f) {
    __hip_bfloat16 h = __float2bfloat16(f);
    return *reinterpret_cast<unsigned short*>(&h);
}
__device__ inline unsigned int pack2bf(float lo, float hi) {
    return (unsigned int)f2bf(lo) | ((unsigned int)f2bf(hi) << 16);
}

// ---------------------------------------------------------------------------
// fp32 -> bf16 convert, 4 elems/thread.
// ---------------------------------------------------------------------------
__global__ __launch_bounds__(256) void cvt_f32_bf16_kernel(const float* __restrict__ src,
                                                           unsigned short* __restrict__ dst,
                                                           int n4) {
    int i = blockIdx.x * 256 + threadIdx.x;
    if (i >= n4) return;
    float4 v = ((const float4*)src)[i];
    ushort4 o;
    o.x = f2bf(v.x); o.y = f2bf(v.y); o.z = f2bf(v.z); o.w = f2bf(v.w);
    ((ushort4*)dst)[i] = o;
}

// ---------------------------------------------------------------------------
// RoPE tables [T][32]: ang(t,i) = t * 10000^(-i/32)
// ---------------------------------------------------------------------------
__global__ __launch_bounds__(256) void rope_table_kernel(float* __restrict__ cosT,
                                                         float* __restrict__ sinT) {
    int idx = blockIdx.x * 256 + threadIdx.x;
    int t = idx >> 5, i = idx & 31;
    float inv_freq = powf(10000.0f, -(float)i / 32.0f);
    float ang = (float)t * inv_freq;
    cosT[idx] = cosf(ang);
    sinT[idx] = sinf(ang);
}

// ---------------------------------------------------------------------------
// bf16 MFMA GEMM (NT), m97 structure (unchanged, HW-verified):
// 128x128 tile, BK=32, 4 waves, 4x4 16x16 frags, global_load_lds w=16.
// ---------------------------------------------------------------------------
#define BM 128
#define BN 128
#define BKK 32

__global__ __launch_bounds__(256) void gemm_bt_mfma(const unsigned short* __restrict__ A,
                                                    const unsigned short* __restrict__ Bm,
                                                    float* __restrict__ Cm,
                                                    int M, int N, int K) {
    __shared__ short As[BM * BKK];
    __shared__ short Bs[BN * BKK];

    const int tid = threadIdx.x;
    const int w = tid >> 6, l = tid & 63;
    const int wr = w >> 1, wc = w & 1;
    const int row0 = blockIdx.x * BM, col0 = blockIdx.y * BN;

    const int srow = w * 16 + (l >> 2);
    const int scol = (l & 3) * 8;

    f32x4 acc[4][4];
#pragma unroll
    for (int m = 0; m < 4; ++m)
#pragma unroll
        for (int n = 0; n < 4; ++n) acc[m][n] = (f32x4){0.f, 0.f, 0.f, 0.f};

    const int fr = l & 15;
    const int fk = (l >> 4) * 8;

    for (int k0 = 0; k0 < K; k0 += BKK) {
        __syncthreads();
#pragma unroll
        for (int half = 0; half < 2; ++half) {
            int r = srow + half * 64;
            GLOAD16(&A[(size_t)(row0 + r) * K + k0 + scol], &As[(half * 64 + w * 16) * BKK]);
            GLOAD16(&Bm[(size_t)(col0 + r) * K + k0 + scol], &Bs[(half * 64 + w * 16) * BKK]);
        }
        __syncthreads();

        short8 af[4], bf[4];
#pragma unroll
        for (int m = 0; m < 4; ++m)
            af[m] = *(const short8*)&As[(wr * 64 + m * 16 + fr) * BKK + fk];
#pragma unroll
        for (int n = 0; n < 4; ++n)
            bf[n] = *(const short8*)&Bs[(wc * 64 + n * 16 + fr) * BKK + fk];
#pragma unroll
        for (int m = 0; m < 4; ++m)
#pragma unroll
            for (int n = 0; n < 4; ++n)
                acc[m][n] = mfma16(af[m], bf[n], acc[m][n]);
    }

    const int crow = (l >> 4) * 4;
    const int ccol = l & 15;
#pragma unroll
    for (int m = 0; m < 4; ++m)
#pragma unroll
        for (int n = 0; n < 4; ++n) {
            size_t base = (size_t)(row0 + wr * 64 + m * 16 + crow) * N + col0 + wc * 64 + n * 16 + ccol;
#pragma unroll
            for (int j = 0; j < 4; ++j) Cm[base + (size_t)j * N] = acc[m][n][j];
        }
}

// ---------------------------------------------------------------------------
// Prep: from fp32 qkv, produce  Kb [bh][1024][64] bf16 (RoPE applied)  and
// VT [bh][64][1024] bf16 (V transposed, via LDS tile). (HW-verified)
// ---------------------------------------------------------------------------
__global__ __launch_bounds__(256) void prep_kernel(const float* __restrict__ qkv,
                                                   const float* __restrict__ cosT,
                                                   const float* __restrict__ sinT,
                                                   unsigned short* __restrict__ Kb,
                                                   unsigned short* __restrict__ VT) {
    const int tt = blockIdx.x, h = blockIdx.y, b = blockIdx.z;
    const int tid = threadIdx.x;
    const int bh = b * H_ + h;
    __shared__ unsigned short Vs[64][68];

#pragma unroll
    for (int p = 0; p < 2; ++p) {
        int tl = p * 32 + (tid >> 3);
        int t = tt * 64 + tl;
        int d0 = (tid & 7) * 4;
        const float* row = qkv + (size_t)(b * T_ + t) * THREEC + C_ + h * D_;
        float4 x0 = *(const float4*)(row + d0);
        float4 x1 = *(const float4*)(row + 32 + d0);
        float4 c = *(const float4*)(cosT + t * 32 + d0);
        float4 s = *(const float4*)(sinT + t * 32 + d0);
        ushort4 o0, o1;
        o0.x = f2bf(x0.x * c.x - x1.x * s.x);  o1.x = f2bf(x1.x * c.x + x0.x * s.x);
        o0.y = f2bf(x0.y * c.y - x1.y * s.y);  o1.y = f2bf(x1.y * c.y + x0.y * s.y);
        o0.z = f2bf(x0.z * c.z - x1.z * s.z);  o1.z = f2bf(x1.z * c.z + x0.z * s.z);
        o0.w = f2bf(x0.w * c.w - x1.w * s.w);  o1.w = f2bf(x1.w * c.w + x0.w * s.w);
        unsigned short* kout = Kb + ((size_t)bh * T_ + t) * D_;
        *(ushort4*)(kout + d0) = o0;
        *(ushort4*)(kout + 32 + d0) = o1;
    }

    {
        int tl = tid >> 2;
        int t = tt * 64 + tl;
        int d0 = (tid & 3) * 16;
        const float* vrow = qkv + (size_t)(b * T_ + t) * THREEC + 2 * C_ + h * D_;
#pragma unroll
        for (int c4 = 0; c4 < 4; ++c4) {
            float4 v = *(const float4*)(vrow + d0 + c4 * 4);
            ushort4 u;
            u.x = f2bf(v.x); u.y = f2bf(v.y); u.z = f2bf(v.z); u.w = f2bf(v.w);
            *(ushort4*)&Vs[tl][d0 + c4 * 4] = u;
        }
    }
    __syncthreads();
    {
        int d = tid >> 2;
        int tc0 = (tid & 3) * 16;
        unsigned short tmp[16];
#pragma unroll
        for (int i = 0; i < 16; ++i) tmp[i] = Vs[tc0 + i][d];
        unsigned short* vout = VT + ((size_t)bh * D_ + d) * T_ + tt * 64 + tc0;
        union { short8 v; unsigned short u[8]; } a0, a1;
#pragma unroll
        for (int i = 0; i < 8; ++i) { a0.u[i] = tmp[i]; a1.u[i] = tmp[8 + i]; }
        *(short8*)vout = a0.v;
        *(short8*)(vout + 8) = a1.v;
    }
}

// ---------------------------------------------------------------------------
// MFMA causal flash attention, v3: QBLK=128 (8 waves); 128 k-rows staged per
// barrier pair as FOUR independent 8KB sub-tiles (Ks0,Ks1,VTs0,VTs1), each in
// the HW-verified 64-tile layout+swizzle; the unchanged 64-row compute body
// runs twice per stage (kt64 = 2*kt+hh). Halves barrier count; no loads in
// flight across barriers (R6 failure class avoided).
// ---------------------------------------------------------------------------
#define QBLK 128

__global__ __launch_bounds__(512) void attn_mfma_kernel(const float* __restrict__ qkv,
                                                        const unsigned short* __restrict__ Kb,
                                                        const unsigned short* __restrict__ VT,
                                                        const float* __restrict__ cosT,
                                                        const float* __restrict__ sinT,
                                                        unsigned short* __restrict__ ao_bf) {
    const int qblk = (T_ / QBLK - 1) - blockIdx.x;  // heavy blocks first
    const int h = blockIdx.y, b = blockIdx.z;
    const int tid = threadIdx.x;
    const int w = tid >> 6, l = tid & 63;           // w = 0..7
    const int g = l >> 4, c = l & 15;
    const int bh = b * H_ + h;

    // staging: Ks0 @0, Ks1 @8192, VTs0 @16384, VTs1 @24576; epilogue overlays
    __shared__ __align__(16) char smem[34816];
    float* Ot = (float*)smem;  // [8 waves][16][68] f32

    const int q_g = qblk * QBLK + w * 16 + c;  // this lane's q row

    // ---- load + RoPE Q in-register, pre-scaled by 2^-3 (exact in bf16) ----
    const float* qrow = qkv + ((size_t)(b * T_) + q_g) * THREEC + h * D_;
    float x0[8], x1[8], cv[8], sv[8];
    *(float4*)&x0[0] = *(const float4*)(qrow + g * 8);
    *(float4*)&x0[4] = *(const float4*)(qrow + g * 8 + 4);
    *(float4*)&x1[0] = *(const float4*)(qrow + 32 + g * 8);
    *(float4*)&x1[4] = *(const float4*)(qrow + 32 + g * 8 + 4);
    *(float4*)&cv[0] = *(const float4*)(cosT + q_g * 32 + g * 8);
    *(float4*)&cv[4] = *(const float4*)(cosT + q_g * 32 + g * 8 + 4);
    *(float4*)&sv[0] = *(const float4*)(sinT + q_g * 32 + g * 8);
    *(float4*)&sv[4] = *(const float4*)(sinT + q_g * 32 + g * 8 + 4);
    union { short8 v; unsigned short u[8]; } qa0, qa1;
#pragma unroll
    for (int j = 0; j < 8; ++j) {
        qa0.u[j] = f2bf((x0[j] * cv[j] - x1[j] * sv[j]) * 0.125f);  // d in [0,32)
        qa1.u[j] = f2bf((x1[j] * cv[j] + x0[j] * sv[j]) * 0.125f);  // d in [32,64)
    }

    f32x4 o[4];
#pragma unroll
    for (int db = 0; db < 4; ++db) o[db] = (f32x4){0.f, 0.f, 0.f, 0.f};
    float m = -INFINITY, lsum = 0.f;

    // staging source-granule swizzle; read-side physical granules
    const int sswz = ((l & 7) ^ (l >> 3)) * 8;
    const int sw0 = (g ^ (c & 7)) * 8;        // logical granule g
    const int sw1 = ((g + 4) ^ (c & 7)) * 8;  // logical granule g+4
    const int srow = w * 8 + (l >> 3);        // staging row 0..63 (8 rows/wave)

    const int nkt = qblk + 1;  // 128-row tiles
    for (int kt = 0; kt < nkt; ++kt) {
        __syncthreads();  // all waves done reading previous stage
        GLOAD16(Kb + ((size_t)bh * T_ + kt * 128 + srow) * D_ + sswz,
                (unsigned short*)smem + (w * 8) * 64);
        GLOAD16(Kb + ((size_t)bh * T_ + kt * 128 + 64 + srow) * D_ + sswz,
                (unsigned short*)(smem + 8192) + (w * 8) * 64);
        GLOAD16(VT + ((size_t)bh * D_ + srow) * T_ + kt * 128 + sswz,
                (unsigned short*)(smem + 16384) + (w * 8) * 64);
        GLOAD16(VT + ((size_t)bh * D_ + srow) * T_ + kt * 128 + 64 + sswz,
                (unsigned short*)(smem + 24576) + (w * 8) * 64);
        __syncthreads();  // staging complete (proven pattern; barrier drains vmcnt)

#pragma unroll
        for (int hh = 0; hh < 2; ++hh) {
            const int kt64 = 2 * kt + hh;
            // wave-uniform skip: this wave's rows are all above this 64-half
            if (kt64 * 64 > qblk * QBLK + w * 16 + 15) continue;

            const unsigned short* Ks  = (const unsigned short*)(smem + hh * 8192);
            const unsigned short* VTs = (const unsigned short*)(smem + 16384 + hh * 8192);

            // ---- S^T tiles: st[t] lane holds S^T[k=kt64*64+t*16+g*4+j][q=c] ----
            f32x4 st[4];
#pragma unroll
            for (int t = 0; t < 4; ++t) {
                short8 k0 = *(const short8*)&Ks[(t * 16 + c) * 64 + sw0];
                short8 k1 = *(const short8*)&Ks[(t * 16 + c) * 64 + sw1];
                f32x4 z = (f32x4){0.f, 0.f, 0.f, 0.f};
                z = mfma16(k0, qa0.v, z);
                st[t] = mfma16(k1, qa1.v, z);
            }

            // ---- causal mask (wave-uniform fast path when fully unmasked) ----
            float p[16];
            float tmax = -INFINITY;
            if (kt64 * 64 + 63 <= qblk * QBLK + w * 16) {
#pragma unroll
                for (int t = 0; t < 4; ++t)
#pragma unroll
                    for (int j = 0; j < 4; ++j) {
                        p[t * 4 + j] = st[t][j];
                        tmax = fmaxf(tmax, st[t][j]);
                    }
            } else {
#pragma unroll
                for (int t = 0; t < 4; ++t)
#pragma unroll
                    for (int j = 0; j < 4; ++j) {
                        int kg = kt64 * 64 + t * 16 + g * 4 + j;
                        float v = (kg <= q_g) ? st[t][j] : -INFINITY;
                        p[t * 4 + j] = v;
                        tmax = fmaxf(tmax, v);
                    }
            }
            tmax = fmaxf(tmax, __shfl_xor(tmax, 16));
            tmax = fmaxf(tmax, __shfl_xor(tmax, 32));
            float mnew = fmaxf(m, tmax);        // finite after tile 0 (diag present)
            float corr = __expf(m - mnew);      // tile 0: exp(-inf)=0, o already 0
            m = mnew;
            float psum = 0.f;
#pragma unroll
            for (int i = 0; i < 16; ++i) { p[i] = __expf(p[i] - m); psum += p[i]; }
            psum += __shfl_xor(psum, 16);
            psum += __shfl_xor(psum, 32);
            lsum = lsum * corr + psum;
#pragma unroll
            for (int db = 0; db < 4; ++db)
#pragma unroll
                for (int j = 0; j < 4; ++j) o[db][j] *= corr;

            // ---- pack P rows to bf16 pairs ----
            unsigned int u[4][2];
#pragma unroll
            for (int t = 0; t < 4; ++t) {
                u[t][0] = pack2bf(p[t * 4 + 0], p[t * 4 + 1]);
                u[t][1] = pack2bf(p[t * 4 + 2], p[t * 4 + 3]);
            }

            // ---- redistribute to P^T B-frags via 8 shfls (HW-verified) ----
            const int srcA = (((g & 1) << 1) | (g >> 1)) * 16 + c;
            const int srcB = (((g & 1) << 1) | ((g >> 1) ^ 1)) * 16 + c;
            const int hi = g >> 1;
            union { short8 v; unsigned int w[4]; } pb[2];
#pragma unroll
            for (int kb = 0; kb < 2; ++kb)
#pragma unroll
                for (int p2 = 0; p2 < 2; ++p2) {
                    unsigned int varA = (g & 1) ? u[kb * 2 + 1][p2] : u[kb * 2][p2];
                    unsigned int varB = (g & 1) ? u[kb * 2][p2] : u[kb * 2 + 1][p2];
                    unsigned int wA = __shfl(varA, srcA, 64);
                    unsigned int wB = __shfl(varB, srcB, 64);
                    pb[kb].w[p2]     = hi ? wB : wA;
                    pb[kb].w[p2 + 2] = hi ? wA : wB;
                }

            // ---- O^T += V^T x P^T ----
#pragma unroll
            for (int db = 0; db < 4; ++db) {
                short8 va0 = *(const short8*)&VTs[(db * 16 + c) * 64 + sw0];
                short8 va1 = *(const short8*)&VTs[(db * 16 + c) * 64 + sw1];
                o[db] = mfma16(va0, pb[0].v, o[db]);
                o[db] = mfma16(va1, pb[1].v, o[db]);
            }
        }
    }

    // ---- epilogue: LDS transpose O^T -> [q][d], write bf16 coalesced ----
    __syncthreads();  // all waves done with staging buffers before overlay
    const float inv = 1.0f / lsum;
    float* ow = Ot + w * 1088;  // wave-private [16][68]
#pragma unroll
    for (int db = 0; db < 4; ++db)
#pragma unroll
        for (int j = 0; j < 4; ++j)
            ow[c * 68 + db * 16 + g * 4 + j] = o[db][j] * inv;
    __syncthreads();
    {
        const float* orow = ow + c * 68 + g * 16;
        f32x4 v0 = *(const f32x4*)(orow);
        f32x4 v1 = *(const f32x4*)(orow + 4);
        f32x4 v2 = *(const f32x4*)(orow + 8);
        f32x4 v3 = *(const f32x4*)(orow + 12);
        union { short8 v; unsigned int w[4]; } s0, s1;
        s0.w[0] = pack2bf(v0[0], v0[1]); s0.w[1] = pack2bf(v0[2], v0[3]);
        s0.w[2] = pack2bf(v1[0], v1[1]); s0.w[3] = pack2bf(v1[2], v1[3]);
        s1.w[0] = pack2bf(v2[0], v2[1]); s1.w[1] = pack2bf(v2[2], v2[3]);
        s1.w[2] = pack2bf(v3[0], v3[1]); s1.w[3] = pack2bf(v3[2], v3[3]);
        unsigned short* op = ao_bf + ((size_t)(b * T_) + qblk * QBLK + w * 16 + c) * C_ + h * D_ + g * 16;
        *(short8*)op = s0.v;
        *(short8*)(op + 8) = s1.v;
    }
}

// ---------------------------------------------------------------------------
// Launch: cvt x3 -> tables -> qkv GEMM -> prep (K rope + V^T) -> attn -> proj
// ---------------------------------------------------------------------------
extern "C" void kernel_launch(void* const* d_in, const int* in_sizes, int n_in,
                              void* d_out, int out_size, void* d_ws, size_t ws_size,
                              hipStream_t stream) {
    const float* x      = (const float*)d_in[0];   // [8192, 768]
    const float* w_qkv  = (const float*)d_in[1];   // [2304, 768]
    const float* w_proj = (const float*)d_in[2];   // [768, 768]
    float* out = (float*)d_out;                    // [8192, 768]

    float* ws   = (float*)d_ws;
    float* qkv  = ws;                              // 18,874,368 f32 (raw QKV)
    float* cosT = ws + 18874368;                   // 32,768 f32
    float* sinT = ws + 18907136;                   // 32,768 f32
    unsigned short* x_bf  = (unsigned short*)(ws + 18939904);  // 6,291,456 bf16
    unsigned short* wq_bf = x_bf + 6291456;        // 1,769,472
    unsigned short* wp_bf = wq_bf + 1769472;       // 589,824
    unsigned short* ao_bf = wp_bf + 589824;        // 6,291,456 (attn out, bf16)
    unsigned short* Kb    = ao_bf + 6291456;       // 6,291,456 (roped K)
    unsigned short* VT    = Kb + 6291456;          // 6,291,456 (V transposed)

    cvt_f32_bf16_kernel<<<6291456 / 4 / 256, 256, 0, stream>>>(x, x_bf, 6291456 / 4);
    cvt_f32_bf16_kernel<<<1769472 / 4 / 256, 256, 0, stream>>>(w_qkv, wq_bf, 1769472 / 4);
    cvt_f32_bf16_kernel<<<589824 / 4 / 256, 256, 0, stream>>>(w_proj, wp_bf, 589824 / 4);
    rope_table_kernel<<<(T_ * 32) / 256, 256, 0, stream>>>(cosT, sinT);

    // qkv = x @ w_qkv^T : M=8192, N=2304, K=768
    gemm_bt_mfma<<<dim3(8192 / BM, 2304 / BN), 256, 0, stream>>>(x_bf, wq_bf, qkv, 8192, 2304, 768);

    prep_kernel<<<dim3(T_ / 64, H_, B_), 256, 0, stream>>>(qkv, cosT, sinT, Kb, VT);

    attn_mfma_kernel<<<dim3(T_ / QBLK, H_, B_), 512, 0, stream>>>(qkv, Kb, VT, cosT, sinT, ao_bf);

    // out = attnout @ w_proj^T : M=8192, N=768, K=768
    gemm_bt_mfma<<<dim3(8192 / BM, 768 / BN), 256, 0, stream>>>(ao_bf, wp_bf, out, 8192, 768, 768);
}